// Round 12
// baseline (257.774 us; speedup 1.0000x reference)
//
#include <hip/hip_runtime.h>
#include <hip/hip_bf16.h>
#include <math.h>

#define BB    8
#define NN    512
#define DD    768
#define DEPD  64

typedef __attribute__((ext_vector_type(4))) float f32x4;
typedef __attribute__((ext_vector_type(8))) short bf16x8;

__device__ __forceinline__ unsigned short to_bf16(float x) {
    __hip_bfloat16 h = __float2bfloat16(x);       // RNE
    return __builtin_bit_cast(unsigned short, h);
}

// 16-lane-row sum via DPP (VALU pipe only); leaves the total in ALL 16 lanes.
__device__ __forceinline__ float dpp_sum16(float x) {
    int t;
    t = __builtin_amdgcn_update_dpp(0, __float_as_int(x), 0xB1, 0xF, 0xF, true);
    x += __int_as_float(t);
    t = __builtin_amdgcn_update_dpp(0, __float_as_int(x), 0x4E, 0xF, 0xF, true);
    x += __int_as_float(t);
    t = __builtin_amdgcn_update_dpp(0, __float_as_int(x), 0x141, 0xF, 0xF, true);
    x += __int_as_float(t);
    t = __builtin_amdgcn_update_dpp(0, __float_as_int(x), 0x140, 0xF, 0xF, true);
    x += __int_as_float(t);
    return x;
}

// ---------------- kernel 1: s_nbr[b,j] = f·w_nbr, s_asp[b,j] = f·w_asp ----
__global__ __launch_bounds__(256) void k_proj(const float* __restrict__ feat,
                                              const float* __restrict__ watt,
                                              float* __restrict__ snbr,
                                              float* __restrict__ sasp)
{
    int flat = blockIdx.x * 4 + (threadIdx.x >> 6);   // b*N + j
    int lane = threadIdx.x & 63;
    const float* frow = feat + (size_t)flat * DD + lane * 4;
    const float* wn   = watt + lane * 4;              // w_nbr = w[:768]
    const float* wa   = watt + DD + DEPD + lane * 4;  // w_asp = w[832:1600]
    float accn = 0.f, acca = 0.f;
#pragma unroll
    for (int k = 0; k < 3; ++k) {
        float4 f = *(const float4*)(frow + k * 256);
        float4 n = *(const float4*)(wn + k * 256);
        float4 a = *(const float4*)(wa + k * 256);
        accn += f.x*n.x + f.y*n.y + f.z*n.z + f.w*n.w;
        acca += f.x*a.x + f.y*a.y + f.z*a.z + f.w*a.w;
    }
#pragma unroll
    for (int off = 1; off < 64; off <<= 1) {
        accn += __shfl_xor(accn, off);
        acca += __shfl_xor(acca, off);
    }
    if (lane == 0) { snbr[flat] = accn; sasp[flat] = acca; }
}

// ---------------- kernel 1b: featT[b][d][j] = bf16(feat[b][j][d]) ---------
__global__ __launch_bounds__(256) void k_cast(const float* __restrict__ feat,
                                              unsigned short* __restrict__ featT)
{
    int b  = blockIdx.z;
    int j0 = blockIdx.y * 64;
    int d0 = blockIdx.x * 64;
    int t  = threadIdx.x;

    __shared__ unsigned short lt[64][65];

    int dd = t & 63, j4 = t >> 6;
#pragma unroll
    for (int it = 0; it < 16; ++it) {
        int jj = j4 * 16 + it;
        float v = feat[((size_t)(b * NN) + (j0 + jj)) * DD + d0 + dd];
        lt[dd][jj] = to_bf16(v);
    }
    __syncthreads();

    int jj2 = t & 63, d4 = t >> 6;
#pragma unroll
    for (int it = 0; it < 16; ++it) {
        int dd2 = d4 * 16 + it;
        featT[((size_t)(b * DD) + (d0 + dd2)) * NN + j0 + jj2] = lt[dd2][jj2];
    }
}

// ---------------- kernel 2: sdep + masked softmax -> bf16 weights ---------
// R10 proven body (ballot + dpp_sum16). LAUNCHED TWICE this round as a
// direct duration measurement (idempotent: same outputs both times).
__global__ __launch_bounds__(256) void k_score(const float* __restrict__ adj,
                                               const float* __restrict__ snbr,
                                               const float* __restrict__ sasp,
                                               const int* __restrict__ aspect,
                                               const float* __restrict__ watt,
                                               unsigned short* __restrict__ wtsB,
                                               int* __restrict__ upd)
{
    int bi  = blockIdx.x;          // b*N + i
    int b   = bi >> 9;
    int tid = threadIdx.x;
    int g = tid >> 4, l = tid & 15;

    __shared__ float sdep[NN];     // -INF = masked
    __shared__ float sred[4];

    float4 wd = *(const float4*)(watt + DD + l * 4);   // w_dep = w[768:832]

    const float* arow = adj + (size_t)bi * NN * DEPD;
#pragma unroll 4
    for (int it = 0; it < NN / 16; ++it) {
        int j = it * 16 + g;
        float4 a = *(const float4*)(arow + (size_t)j * DEPD + l * 4);
        float p  = a.x*wd.x + a.y*wd.y + a.z*wd.z + a.w*wd.w;
        int   nz = (a.x != 0.f) | (a.y != 0.f) | (a.z != 0.f) | (a.w != 0.f);
        unsigned long long bal = __ballot(nz);
        unsigned int gnz = (unsigned int)((bal >> ((g & 3) * 16)) & 0xFFFFull);
        p = dpp_sum16(p);                              // VALU-only 16-lane sum
        if (l == 0) sdep[j] = gnz ? p : -INFINITY;
    }
    __syncthreads();

    float sa = sasp[bi];
    int j0 = tid, j1 = tid + 256;
    float d0 = sdep[j0], d1 = sdep[j1];
    float sc0 = d0 + snbr[(b << 9) + j0] + sa;   // -INF stays -INF
    float sc1 = d1 + snbr[(b << 9) + j1] + sa;

    float v = fmaxf(sc0, sc1);
#pragma unroll
    for (int off = 1; off < 64; off <<= 1) v = fmaxf(v, __shfl_xor(v, off));
    if ((tid & 63) == 0) sred[tid >> 6] = v;
    __syncthreads();
    float mx = fmaxf(fmaxf(sred[0], sred[1]), fmaxf(sred[2], sred[3]));
    __syncthreads();

    float e0 = d0 > -1e37f ? __expf(sc0 - mx) : 0.f;
    float e1 = d1 > -1e37f ? __expf(sc1 - mx) : 0.f;
    v = e0 + e1;
#pragma unroll
    for (int off = 1; off < 64; off <<= 1) v += __shfl_xor(v, off);
    if ((tid & 63) == 0) sred[tid >> 6] = v;
    __syncthreads();
    float sm = sred[0] + sred[1] + sred[2] + sred[3];

    float inv = sm > 0.f ? 1.f / sm : 0.f;
    size_t wb = (size_t)bi * NN;
    wtsB[wb + j0] = to_bf16(e0 * inv);     // coalesced 2B stores
    wtsB[wb + j1] = to_bf16(e1 * inv);
    if (tid == 0) upd[bi] = (aspect[bi] != 0) && (mx > -1e37f);
}

// ---------------- kernel 3: MFMA agg, XCD-pinned by batch ------------------
// (verbatim R8)
__global__ __launch_bounds__(256) void k_agg(const unsigned short* __restrict__ wtsB,
                                             const unsigned short* __restrict__ featT,
                                             const float* __restrict__ feat,
                                             const int* __restrict__ upd,
                                             float* __restrict__ out)
{
    int blk  = blockIdx.x;
    int b    = blk & 7;            // XCD pin
    int rem  = blk >> 3;           // 0..383
    int dblk = rem % 24;
    int iblk = rem / 24;           // 0..15

    int wave = threadIdx.x >> 6;
    int l    = threadIdx.x & 63;
    int i0   = iblk * 32 + (wave >> 1) * 16;
    int d0   = dblk * 32 + (wave & 1) * 16;
    int lr   = l & 15, lg = l >> 4;

    const unsigned short* wrow = wtsB  + ((size_t)(b * NN + i0 + lr)) * NN + lg * 8;
    const unsigned short* frow = featT + ((size_t)(b * DD + d0 + lr)) * NN + lg * 8;

    f32x4 acc = {0.f, 0.f, 0.f, 0.f};
#pragma unroll
    for (int k = 0; k < NN; k += 32) {
        bf16x8 av = *(const bf16x8*)(wrow + k);
        bf16x8 bv = *(const bf16x8*)(frow + k);
        acc = __builtin_amdgcn_mfma_f32_16x16x32_bf16(av, bv, acc, 0, 0, 0);
    }

    int dcol = d0 + lr;
#pragma unroll
    for (int reg = 0; reg < 4; ++reg) {
        int ii   = i0 + lg * 4 + reg;
        int rowi = b * NN + ii;
        float o  = upd[rowi] ? acc[reg] : feat[(size_t)rowi * DD + dcol];
        out[(size_t)rowi * DD + dcol] = o;
    }
}

extern "C" void kernel_launch(void* const* d_in, const int* in_sizes, int n_in,
                              void* d_out, int out_size, void* d_ws, size_t ws_size,
                              hipStream_t stream)
{
    (void)in_sizes; (void)n_in; (void)out_size; (void)ws_size;
    const float* feat = (const float*)d_in[0];
    const int*   asp  = (const int*)d_in[1];
    const float* adj  = (const float*)d_in[2];
    const float* watt = (const float*)d_in[3];
    float* out = (float*)d_out;

    // workspace: wtsB bf16 [8][512][512] (4MB) | featT bf16 [8][768][512]
    // (6.3MB) | snbr | sasp | upd
    unsigned short* wtsB  = (unsigned short*)d_ws;
    unsigned short* featT = wtsB + (size_t)BB * NN * NN;
    float* snbr = (float*)(featT + (size_t)BB * DD * NN);
    float* sasp = snbr + BB * NN;
    int*   upd  = (int*)(sasp + BB * NN);

    k_proj<<<BB * NN / 4, 256, 0, stream>>>(feat, watt, snbr, sasp);
    dim3 gc(DD / 64, NN / 64, BB);
    k_cast<<<gc, 256, 0, stream>>>(feat, featT);
    // DIAGNOSTIC: k_score launched twice (idempotent). dur_us - 162.3 = score.
    k_score<<<BB * NN, 256, 0, stream>>>(adj, snbr, sasp, asp, watt, wtsB, upd);
    k_score<<<BB * NN, 256, 0, stream>>>(adj, snbr, sasp, asp, watt, wtsB, upd);
    k_agg<<<BB * (NN / 32) * (DD / 32), 256, 0, stream>>>(wtsB, featT, feat, upd, out);
}

// Round 13
// 146.940 us; speedup vs baseline: 1.7543x; 1.7543x over previous
//
#include <hip/hip_runtime.h>
#include <hip/hip_bf16.h>
#include <math.h>

#define BB    8
#define NN    512
#define DD    768
#define DEPD  64

typedef __attribute__((ext_vector_type(4))) float f32x4;
typedef __attribute__((ext_vector_type(8))) short bf16x8;

__device__ __forceinline__ unsigned short to_bf16(float x) {
    __hip_bfloat16 h = __float2bfloat16(x);       // RNE
    return __builtin_bit_cast(unsigned short, h);
}

// 16-lane-row sum via DPP (VALU pipe only); leaves the total in ALL 16 lanes.
__device__ __forceinline__ float dpp_sum16(float x) {
    int t;
    t = __builtin_amdgcn_update_dpp(0, __float_as_int(x), 0xB1, 0xF, 0xF, true);
    x += __int_as_float(t);
    t = __builtin_amdgcn_update_dpp(0, __float_as_int(x), 0x4E, 0xF, 0xF, true);
    x += __int_as_float(t);
    t = __builtin_amdgcn_update_dpp(0, __float_as_int(x), 0x141, 0xF, 0xF, true);
    x += __int_as_float(t);
    t = __builtin_amdgcn_update_dpp(0, __float_as_int(x), 0x140, 0xF, 0xF, true);
    x += __int_as_float(t);
    return x;
}

// ---------------- kernel 1: s_nbr[b,j] = f·w_nbr, s_asp[b,j] = f·w_asp ----
__global__ __launch_bounds__(256) void k_proj(const float* __restrict__ feat,
                                              const float* __restrict__ watt,
                                              float* __restrict__ snbr,
                                              float* __restrict__ sasp)
{
    int flat = blockIdx.x * 4 + (threadIdx.x >> 6);   // b*N + j
    int lane = threadIdx.x & 63;
    const float* frow = feat + (size_t)flat * DD + lane * 4;
    const float* wn   = watt + lane * 4;              // w_nbr = w[:768]
    const float* wa   = watt + DD + DEPD + lane * 4;  // w_asp = w[832:1600]
    float accn = 0.f, acca = 0.f;
#pragma unroll
    for (int k = 0; k < 3; ++k) {
        float4 f = *(const float4*)(frow + k * 256);
        float4 n = *(const float4*)(wn + k * 256);
        float4 a = *(const float4*)(wa + k * 256);
        accn += f.x*n.x + f.y*n.y + f.z*n.z + f.w*n.w;
        acca += f.x*a.x + f.y*a.y + f.z*a.z + f.w*a.w;
    }
#pragma unroll
    for (int off = 1; off < 64; off <<= 1) {
        accn += __shfl_xor(accn, off);
        acca += __shfl_xor(acca, off);
    }
    if (lane == 0) { snbr[flat] = accn; sasp[flat] = acca; }
}

// ---------------- kernel 1b: featT[b][d][j] = bf16(feat[b][j][d]) ---------
__global__ __launch_bounds__(256) void k_cast(const float* __restrict__ feat,
                                              unsigned short* __restrict__ featT)
{
    int b  = blockIdx.z;
    int j0 = blockIdx.y * 64;
    int d0 = blockIdx.x * 64;
    int t  = threadIdx.x;

    __shared__ unsigned short lt[64][65];

    int dd = t & 63, j4 = t >> 6;
#pragma unroll
    for (int it = 0; it < 16; ++it) {
        int jj = j4 * 16 + it;
        float v = feat[((size_t)(b * NN) + (j0 + jj)) * DD + d0 + dd];
        lt[dd][jj] = to_bf16(v);
    }
    __syncthreads();

    int jj2 = t & 63, d4 = t >> 6;
#pragma unroll
    for (int it = 0; it < 16; ++it) {
        int dd2 = d4 * 16 + it;
        featT[((size_t)(b * DD) + (d0 + dd2)) * NN + j0 + jj2] = lt[dd2][jj2];
    }
}

// ---------------- kernel 2: sdep + masked softmax -> bf16 weights ---------
// R10 proven body. Measured R12: ~95 us = 5.65 TB/s on the 537MB stream
// (88-90% of achievable HBM BW) -> at roofline, do not touch.
__global__ __launch_bounds__(256) void k_score(const float* __restrict__ adj,
                                               const float* __restrict__ snbr,
                                               const float* __restrict__ sasp,
                                               const int* __restrict__ aspect,
                                               const float* __restrict__ watt,
                                               unsigned short* __restrict__ wtsB,
                                               int* __restrict__ upd)
{
    int bi  = blockIdx.x;          // b*N + i
    int b   = bi >> 9;
    int tid = threadIdx.x;
    int g = tid >> 4, l = tid & 15;

    __shared__ float sdep[NN];     // -INF = masked
    __shared__ float sred[4];

    float4 wd = *(const float4*)(watt + DD + l * 4);   // w_dep = w[768:832]

    const float* arow = adj + (size_t)bi * NN * DEPD;
#pragma unroll 4
    for (int it = 0; it < NN / 16; ++it) {
        int j = it * 16 + g;
        float4 a = *(const float4*)(arow + (size_t)j * DEPD + l * 4);
        float p  = a.x*wd.x + a.y*wd.y + a.z*wd.z + a.w*wd.w;
        int   nz = (a.x != 0.f) | (a.y != 0.f) | (a.z != 0.f) | (a.w != 0.f);
        unsigned long long bal = __ballot(nz);
        unsigned int gnz = (unsigned int)((bal >> ((g & 3) * 16)) & 0xFFFFull);
        p = dpp_sum16(p);                              // VALU-only 16-lane sum
        if (l == 0) sdep[j] = gnz ? p : -INFINITY;
    }
    __syncthreads();

    float sa = sasp[bi];
    int j0 = tid, j1 = tid + 256;
    float d0 = sdep[j0], d1 = sdep[j1];
    float sc0 = d0 + snbr[(b << 9) + j0] + sa;   // -INF stays -INF
    float sc1 = d1 + snbr[(b << 9) + j1] + sa;

    float v = fmaxf(sc0, sc1);
#pragma unroll
    for (int off = 1; off < 64; off <<= 1) v = fmaxf(v, __shfl_xor(v, off));
    if ((tid & 63) == 0) sred[tid >> 6] = v;
    __syncthreads();
    float mx = fmaxf(fmaxf(sred[0], sred[1]), fmaxf(sred[2], sred[3]));
    __syncthreads();

    float e0 = d0 > -1e37f ? __expf(sc0 - mx) : 0.f;
    float e1 = d1 > -1e37f ? __expf(sc1 - mx) : 0.f;
    v = e0 + e1;
#pragma unroll
    for (int off = 1; off < 64; off <<= 1) v += __shfl_xor(v, off);
    if ((tid & 63) == 0) sred[tid >> 6] = v;
    __syncthreads();
    float sm = sred[0] + sred[1] + sred[2] + sred[3];

    float inv = sm > 0.f ? 1.f / sm : 0.f;
    size_t wb = (size_t)bi * NN;
    wtsB[wb + j0] = to_bf16(e0 * inv);     // coalesced 2B stores
    wtsB[wb + j1] = to_bf16(e1 * inv);
    if (tid == 0) upd[bi] = (aspect[bi] != 0) && (mx > -1e37f);
}

// ---------------- kernel 3: MFMA agg, 2x2 register-blocked ----------------
// Wave computes 32x32 (2x2 frags, 4 MFMA per 2A+2B loads -> AI 16 FLOP/B,
// halves L2 tile re-read traffic vs R8). Block = 4 waves = 64x64 tile.
// Grid 768 = 8 x 96, b = blk & 7 keeps the XCD pin.
__global__ __launch_bounds__(256) void k_agg(const unsigned short* __restrict__ wtsB,
                                             const unsigned short* __restrict__ featT,
                                             const float* __restrict__ feat,
                                             const int* __restrict__ upd,
                                             float* __restrict__ out)
{
    int blk  = blockIdx.x;
    int b    = blk & 7;            // XCD pin
    int rem  = blk >> 3;           // 0..95
    int dblk = rem % 12;
    int iblk = rem / 12;           // 0..7

    int wave = threadIdx.x >> 6;
    int l    = threadIdx.x & 63;
    int i0w  = iblk * 64 + (wave >> 1) * 32;
    int d0w  = dblk * 64 + (wave & 1) * 32;
    int lr   = l & 15, lg = l >> 4;

    const unsigned short* wr0 = wtsB  + ((size_t)(b * NN + i0w + lr)) * NN + lg * 8;
    const unsigned short* wr1 = wr0 + 16 * NN;
    const unsigned short* fr0 = featT + ((size_t)(b * DD + d0w + lr)) * NN + lg * 8;
    const unsigned short* fr1 = fr0 + 16 * NN;

    f32x4 acc00 = {0.f,0.f,0.f,0.f}, acc01 = {0.f,0.f,0.f,0.f};
    f32x4 acc10 = {0.f,0.f,0.f,0.f}, acc11 = {0.f,0.f,0.f,0.f};

#pragma unroll
    for (int k = 0; k < NN; k += 32) {
        bf16x8 a0 = *(const bf16x8*)(wr0 + k);
        bf16x8 a1 = *(const bf16x8*)(wr1 + k);
        bf16x8 b0 = *(const bf16x8*)(fr0 + k);
        bf16x8 b1 = *(const bf16x8*)(fr1 + k);
        acc00 = __builtin_amdgcn_mfma_f32_16x16x32_bf16(a0, b0, acc00, 0, 0, 0);
        acc01 = __builtin_amdgcn_mfma_f32_16x16x32_bf16(a0, b1, acc01, 0, 0, 0);
        acc10 = __builtin_amdgcn_mfma_f32_16x16x32_bf16(a1, b0, acc10, 0, 0, 0);
        acc11 = __builtin_amdgcn_mfma_f32_16x16x32_bf16(a1, b1, acc11, 0, 0, 0);
    }

#pragma unroll
    for (int ai = 0; ai < 2; ++ai) {
#pragma unroll
        for (int reg = 0; reg < 4; ++reg) {
            int ii   = i0w + ai * 16 + lg * 4 + reg;
            int rowi = b * NN + ii;
            size_t rb = (size_t)rowi * DD;
            int up = upd[rowi];
            const f32x4& aL = ai ? acc10 : acc00;
            const f32x4& aR = ai ? acc11 : acc01;
            int c0 = d0w + lr, c1 = d0w + 16 + lr;
            out[rb + c0] = up ? aL[reg] : feat[rb + c0];
            out[rb + c1] = up ? aR[reg] : feat[rb + c1];
        }
    }
}

extern "C" void kernel_launch(void* const* d_in, const int* in_sizes, int n_in,
                              void* d_out, int out_size, void* d_ws, size_t ws_size,
                              hipStream_t stream)
{
    (void)in_sizes; (void)n_in; (void)out_size; (void)ws_size;
    const float* feat = (const float*)d_in[0];
    const int*   asp  = (const int*)d_in[1];
    const float* adj  = (const float*)d_in[2];
    const float* watt = (const float*)d_in[3];
    float* out = (float*)d_out;

    // workspace: wtsB bf16 [8][512][512] (4MB) | featT bf16 [8][768][512]
    // (6.3MB) | snbr | sasp | upd
    unsigned short* wtsB  = (unsigned short*)d_ws;
    unsigned short* featT = wtsB + (size_t)BB * NN * NN;
    float* snbr = (float*)(featT + (size_t)BB * DD * NN);
    float* sasp = snbr + BB * NN;
    int*   upd  = (int*)(sasp + BB * NN);

    k_proj<<<BB * NN / 4, 256, 0, stream>>>(feat, watt, snbr, sasp);
    dim3 gc(DD / 64, NN / 64, BB);
    k_cast<<<gc, 256, 0, stream>>>(feat, featT);
    k_score<<<BB * NN, 256, 0, stream>>>(adj, snbr, sasp, asp, watt, wtsB, upd);
    k_agg<<<BB * (NN / 64) * (DD / 64), 256, 0, stream>>>(wtsB, featT, feat, upd, out);
}

// Round 14
// 142.927 us; speedup vs baseline: 1.8035x; 1.0281x over previous
//
#include <hip/hip_runtime.h>
#include <hip/hip_bf16.h>
#include <math.h>

#define BB    8
#define NN    512
#define DD    768
#define DEPD  64

typedef __attribute__((ext_vector_type(4))) float f32x4;
typedef __attribute__((ext_vector_type(8))) short bf16x8;

__device__ __forceinline__ unsigned short to_bf16(float x) {
    __hip_bfloat16 h = __float2bfloat16(x);       // RNE
    return __builtin_bit_cast(unsigned short, h);
}

// 16-lane-row sum via DPP (VALU pipe only); leaves the total in ALL 16 lanes.
__device__ __forceinline__ float dpp_sum16(float x) {
    int t;
    t = __builtin_amdgcn_update_dpp(0, __float_as_int(x), 0xB1, 0xF, 0xF, true);
    x += __int_as_float(t);
    t = __builtin_amdgcn_update_dpp(0, __float_as_int(x), 0x4E, 0xF, 0xF, true);
    x += __int_as_float(t);
    t = __builtin_amdgcn_update_dpp(0, __float_as_int(x), 0x141, 0xF, 0xF, true);
    x += __int_as_float(t);
    t = __builtin_amdgcn_update_dpp(0, __float_as_int(x), 0x140, 0xF, 0xF, true);
    x += __int_as_float(t);
    return x;
}

// ---------------- kernel 1: fused prep ------------------------------------
// blk < 768 : featT[b][d][j] = bf16(feat[b][j][d])   (cast body, verbatim)
// blk >= 768: snbr[b,j] = feat[b,j,:]·w_nbr          (proj body, snbr only —
//   s_asp is constant along the softmax axis j and cancels exactly, so the
//   whole s_asp pathway is removed as a mathematical identity)
__global__ __launch_bounds__(256) void k_prep(const float* __restrict__ feat,
                                              const float* __restrict__ watt,
                                              unsigned short* __restrict__ featT,
                                              float* __restrict__ snbr)
{
    int blk = blockIdx.x;
    int t   = threadIdx.x;

    if (blk < 768) {                                  // ---- cast tile ----
        int b  = blk / 96;
        int j0 = ((blk / 12) % 8) * 64;
        int d0 = (blk % 12) * 64;

        __shared__ unsigned short lt[64][65];

        int dd = t & 63, j4 = t >> 6;
#pragma unroll
        for (int it = 0; it < 16; ++it) {
            int jj = j4 * 16 + it;
            float v = feat[((size_t)(b * NN) + (j0 + jj)) * DD + d0 + dd];
            lt[dd][jj] = to_bf16(v);
        }
        __syncthreads();

        int jj2 = t & 63, d4 = t >> 6;
#pragma unroll
        for (int it = 0; it < 16; ++it) {
            int dd2 = d4 * 16 + it;
            featT[((size_t)(b * DD) + (d0 + dd2)) * NN + j0 + jj2] = lt[dd2][jj2];
        }
    } else {                                          // ---- proj rows ----
        int pb   = blk - 768;                         // 0..1023
        int flat = pb * 4 + (t >> 6);                 // b*N + j
        int lane = t & 63;
        const float* frow = feat + (size_t)flat * DD + lane * 4;
        const float* wn   = watt + lane * 4;          // w_nbr = w[:768]
        float accn = 0.f;
#pragma unroll
        for (int k = 0; k < 3; ++k) {
            float4 f = *(const float4*)(frow + k * 256);
            float4 n = *(const float4*)(wn + k * 256);
            accn += f.x*n.x + f.y*n.y + f.z*n.z + f.w*n.w;
        }
#pragma unroll
        for (int off = 1; off < 64; off <<= 1)
            accn += __shfl_xor(accn, off);
        if (lane == 0) snbr[flat] = accn;
    }
}

// ---------------- kernel 2: sdep + masked softmax -> bf16 weights ---------
// R10/R13 proven body; s_asp dropped (exact softmax identity). Measured
// R12: ~95 us = 5.65 TB/s on the 537MB stream -> at HBM roofline.
__global__ __launch_bounds__(256) void k_score(const float* __restrict__ adj,
                                               const float* __restrict__ snbr,
                                               const int* __restrict__ aspect,
                                               const float* __restrict__ watt,
                                               unsigned short* __restrict__ wtsB,
                                               int* __restrict__ upd)
{
    int bi  = blockIdx.x;          // b*N + i
    int b   = bi >> 9;
    int tid = threadIdx.x;
    int g = tid >> 4, l = tid & 15;

    __shared__ float sdep[NN];     // -INF = masked
    __shared__ float sred[4];

    float4 wd = *(const float4*)(watt + DD + l * 4);   // w_dep = w[768:832]

    const float* arow = adj + (size_t)bi * NN * DEPD;
#pragma unroll 4
    for (int it = 0; it < NN / 16; ++it) {
        int j = it * 16 + g;
        float4 a = *(const float4*)(arow + (size_t)j * DEPD + l * 4);
        float p  = a.x*wd.x + a.y*wd.y + a.z*wd.z + a.w*wd.w;
        int   nz = (a.x != 0.f) | (a.y != 0.f) | (a.z != 0.f) | (a.w != 0.f);
        unsigned long long bal = __ballot(nz);
        unsigned int gnz = (unsigned int)((bal >> ((g & 3) * 16)) & 0xFFFFull);
        p = dpp_sum16(p);                              // VALU-only 16-lane sum
        if (l == 0) sdep[j] = gnz ? p : -INFINITY;
    }
    __syncthreads();

    int j0 = tid, j1 = tid + 256;
    float d0 = sdep[j0], d1 = sdep[j1];
    float sc0 = d0 + snbr[(b << 9) + j0];        // -INF stays -INF
    float sc1 = d1 + snbr[(b << 9) + j1];

    float v = fmaxf(sc0, sc1);
#pragma unroll
    for (int off = 1; off < 64; off <<= 1) v = fmaxf(v, __shfl_xor(v, off));
    if ((tid & 63) == 0) sred[tid >> 6] = v;
    __syncthreads();
    float mx = fmaxf(fmaxf(sred[0], sred[1]), fmaxf(sred[2], sred[3]));
    __syncthreads();

    float e0 = d0 > -1e37f ? __expf(sc0 - mx) : 0.f;
    float e1 = d1 > -1e37f ? __expf(sc1 - mx) : 0.f;
    v = e0 + e1;
#pragma unroll
    for (int off = 1; off < 64; off <<= 1) v += __shfl_xor(v, off);
    if ((tid & 63) == 0) sred[tid >> 6] = v;
    __syncthreads();
    float sm = sred[0] + sred[1] + sred[2] + sred[3];

    float inv = sm > 0.f ? 1.f / sm : 0.f;
    size_t wb = (size_t)bi * NN;
    wtsB[wb + j0] = to_bf16(e0 * inv);     // coalesced 2B stores
    wtsB[wb + j1] = to_bf16(e1 * inv);
    if (tid == 0) upd[bi] = (aspect[bi] != 0) && (mx > -1e37f);
}

// ---------------- kernel 3: MFMA agg, 2x2 register-blocked ----------------
// (verbatim R13: wave = 32x32 via 4 MFMA per 2A+2B frags; block 64x64;
//  grid 768 = 8 x 96 with XCD pin b = blk & 7)
__global__ __launch_bounds__(256) void k_agg(const unsigned short* __restrict__ wtsB,
                                             const unsigned short* __restrict__ featT,
                                             const float* __restrict__ feat,
                                             const int* __restrict__ upd,
                                             float* __restrict__ out)
{
    int blk  = blockIdx.x;
    int b    = blk & 7;            // XCD pin
    int rem  = blk >> 3;           // 0..95
    int dblk = rem % 12;
    int iblk = rem / 12;           // 0..7

    int wave = threadIdx.x >> 6;
    int l    = threadIdx.x & 63;
    int i0w  = iblk * 64 + (wave >> 1) * 32;
    int d0w  = dblk * 64 + (wave & 1) * 32;
    int lr   = l & 15, lg = l >> 4;

    const unsigned short* wr0 = wtsB  + ((size_t)(b * NN + i0w + lr)) * NN + lg * 8;
    const unsigned short* wr1 = wr0 + 16 * NN;
    const unsigned short* fr0 = featT + ((size_t)(b * DD + d0w + lr)) * NN + lg * 8;
    const unsigned short* fr1 = fr0 + 16 * NN;

    f32x4 acc00 = {0.f,0.f,0.f,0.f}, acc01 = {0.f,0.f,0.f,0.f};
    f32x4 acc10 = {0.f,0.f,0.f,0.f}, acc11 = {0.f,0.f,0.f,0.f};

#pragma unroll
    for (int k = 0; k < NN; k += 32) {
        bf16x8 a0 = *(const bf16x8*)(wr0 + k);
        bf16x8 a1 = *(const bf16x8*)(wr1 + k);
        bf16x8 b0 = *(const bf16x8*)(fr0 + k);
        bf16x8 b1 = *(const bf16x8*)(fr1 + k);
        acc00 = __builtin_amdgcn_mfma_f32_16x16x32_bf16(a0, b0, acc00, 0, 0, 0);
        acc01 = __builtin_amdgcn_mfma_f32_16x16x32_bf16(a0, b1, acc01, 0, 0, 0);
        acc10 = __builtin_amdgcn_mfma_f32_16x16x32_bf16(a1, b0, acc10, 0, 0, 0);
        acc11 = __builtin_amdgcn_mfma_f32_16x16x32_bf16(a1, b1, acc11, 0, 0, 0);
    }

#pragma unroll
    for (int ai = 0; ai < 2; ++ai) {
#pragma unroll
        for (int reg = 0; reg < 4; ++reg) {
            int ii   = i0w + ai * 16 + lg * 4 + reg;
            int rowi = b * NN + ii;
            size_t rb = (size_t)rowi * DD;
            int up = upd[rowi];
            const f32x4& aL = ai ? acc10 : acc00;
            const f32x4& aR = ai ? acc11 : acc01;
            int c0 = d0w + lr, c1 = d0w + 16 + lr;
            out[rb + c0] = up ? aL[reg] : feat[rb + c0];
            out[rb + c1] = up ? aR[reg] : feat[rb + c1];
        }
    }
}

extern "C" void kernel_launch(void* const* d_in, const int* in_sizes, int n_in,
                              void* d_out, int out_size, void* d_ws, size_t ws_size,
                              hipStream_t stream)
{
    (void)in_sizes; (void)n_in; (void)out_size; (void)ws_size;
    const float* feat = (const float*)d_in[0];
    const int*   asp  = (const int*)d_in[1];
    const float* adj  = (const float*)d_in[2];
    const float* watt = (const float*)d_in[3];
    float* out = (float*)d_out;

    // workspace: wtsB bf16 [8][512][512] (4MB) | featT bf16 [8][768][512]
    // (6.3MB) | snbr | upd
    unsigned short* wtsB  = (unsigned short*)d_ws;
    unsigned short* featT = wtsB + (size_t)BB * NN * NN;
    float* snbr = (float*)(featT + (size_t)BB * DD * NN);
    int*   upd  = (int*)(snbr + BB * NN);

    k_prep<<<768 + 1024, 256, 0, stream>>>(feat, watt, featT, snbr);
    k_score<<<BB * NN, 256, 0, stream>>>(adj, snbr, asp, watt, wtsB, upd);
    k_agg<<<BB * (NN / 64) * (DD / 64), 256, 0, stream>>>(wtsB, featT, feat, upd, out);
}

// Round 15
// 122.685 us; speedup vs baseline: 2.1011x; 1.1650x over previous
//
#include <hip/hip_runtime.h>
#include <hip/hip_bf16.h>
#include <math.h>

#define BB    8
#define NN    512
#define DD    768
#define DEPD  64

typedef __attribute__((ext_vector_type(4))) float f32x4;
typedef __attribute__((ext_vector_type(8))) short bf16x8;

__device__ __forceinline__ unsigned short to_bf16(float x) {
    __hip_bfloat16 h = __float2bfloat16(x);       // RNE
    return __builtin_bit_cast(unsigned short, h);
}

// 16-lane-row sum via DPP (VALU pipe only); leaves the total in ALL 16 lanes.
__device__ __forceinline__ float dpp_sum16(float x) {
    int t;
    t = __builtin_amdgcn_update_dpp(0, __float_as_int(x), 0xB1, 0xF, 0xF, true);
    x += __int_as_float(t);
    t = __builtin_amdgcn_update_dpp(0, __float_as_int(x), 0x4E, 0xF, 0xF, true);
    x += __int_as_float(t);
    t = __builtin_amdgcn_update_dpp(0, __float_as_int(x), 0x141, 0xF, 0xF, true);
    x += __int_as_float(t);
    t = __builtin_amdgcn_update_dpp(0, __float_as_int(x), 0x140, 0xF, 0xF, true);
    x += __int_as_float(t);
    return x;
}

// ---------------- kernel 1: fused prep (verbatim R14) ---------------------
__global__ __launch_bounds__(256) void k_prep(const float* __restrict__ feat,
                                              const float* __restrict__ watt,
                                              unsigned short* __restrict__ featT,
                                              float* __restrict__ snbr)
{
    int blk = blockIdx.x;
    int t   = threadIdx.x;

    if (blk < 768) {                                  // ---- cast tile ----
        int b  = blk / 96;
        int j0 = ((blk / 12) % 8) * 64;
        int d0 = (blk % 12) * 64;

        __shared__ unsigned short lt[64][65];

        int dd = t & 63, j4 = t >> 6;
#pragma unroll
        for (int it = 0; it < 16; ++it) {
            int jj = j4 * 16 + it;
            float v = feat[((size_t)(b * NN) + (j0 + jj)) * DD + d0 + dd];
            lt[dd][jj] = to_bf16(v);
        }
        __syncthreads();

        int jj2 = t & 63, d4 = t >> 6;
#pragma unroll
        for (int it = 0; it < 16; ++it) {
            int dd2 = d4 * 16 + it;
            featT[((size_t)(b * DD) + (d0 + dd2)) * NN + j0 + jj2] = lt[dd2][jj2];
        }
    } else {                                          // ---- proj rows ----
        int pb   = blk - 768;                         // 0..1023
        int flat = pb * 4 + (t >> 6);                 // b*N + j
        int lane = t & 63;
        const float* frow = feat + (size_t)flat * DD + lane * 4;
        const float* wn   = watt + lane * 4;          // w_nbr = w[:768]
        float accn = 0.f;
#pragma unroll
        for (int k = 0; k < 3; ++k) {
            float4 f = *(const float4*)(frow + k * 256);
            float4 n = *(const float4*)(wn + k * 256);
            accn += f.x*n.x + f.y*n.y + f.z*n.z + f.w*n.w;
        }
#pragma unroll
        for (int off = 1; off < 64; off <<= 1)
            accn += __shfl_xor(accn, off);
        if (lane == 0) snbr[flat] = accn;
    }
}

// ---------------- kernel 2: sdep + masked softmax -> bf16 weights ---------
// R14 body; ONLY change: adj loads are NON-TEMPORAL (read-once stream, do
// not allocate in L2/L3 -> wtsB/featT stay cache-resident for k_agg).
__global__ __launch_bounds__(256) void k_score(const float* __restrict__ adj,
                                               const float* __restrict__ snbr,
                                               const int* __restrict__ aspect,
                                               const float* __restrict__ watt,
                                               unsigned short* __restrict__ wtsB,
                                               int* __restrict__ upd)
{
    int bi  = blockIdx.x;          // b*N + i
    int b   = bi >> 9;
    int tid = threadIdx.x;
    int g = tid >> 4, l = tid & 15;

    __shared__ float sdep[NN];     // -INF = masked
    __shared__ float sred[4];

    float4 wd = *(const float4*)(watt + DD + l * 4);   // w_dep = w[768:832]

    const float* arow = adj + (size_t)bi * NN * DEPD;
#pragma unroll 4
    for (int it = 0; it < NN / 16; ++it) {
        int j = it * 16 + g;
        f32x4 a = __builtin_nontemporal_load(
                      (const f32x4*)(arow + (size_t)j * DEPD + l * 4));
        float p  = a[0]*wd.x + a[1]*wd.y + a[2]*wd.z + a[3]*wd.w;
        int   nz = (a[0] != 0.f) | (a[1] != 0.f) | (a[2] != 0.f) | (a[3] != 0.f);
        unsigned long long bal = __ballot(nz);
        unsigned int gnz = (unsigned int)((bal >> ((g & 3) * 16)) & 0xFFFFull);
        p = dpp_sum16(p);                              // VALU-only 16-lane sum
        if (l == 0) sdep[j] = gnz ? p : -INFINITY;
    }
    __syncthreads();

    int j0 = tid, j1 = tid + 256;
    float d0 = sdep[j0], d1 = sdep[j1];
    float sc0 = d0 + snbr[(b << 9) + j0];        // -INF stays -INF
    float sc1 = d1 + snbr[(b << 9) + j1];

    float v = fmaxf(sc0, sc1);
#pragma unroll
    for (int off = 1; off < 64; off <<= 1) v = fmaxf(v, __shfl_xor(v, off));
    if ((tid & 63) == 0) sred[tid >> 6] = v;
    __syncthreads();
    float mx = fmaxf(fmaxf(sred[0], sred[1]), fmaxf(sred[2], sred[3]));
    __syncthreads();

    float e0 = d0 > -1e37f ? __expf(sc0 - mx) : 0.f;
    float e1 = d1 > -1e37f ? __expf(sc1 - mx) : 0.f;
    v = e0 + e1;
#pragma unroll
    for (int off = 1; off < 64; off <<= 1) v += __shfl_xor(v, off);
    if ((tid & 63) == 0) sred[tid >> 6] = v;
    __syncthreads();
    float sm = sred[0] + sred[1] + sred[2] + sred[3];

    float inv = sm > 0.f ? 1.f / sm : 0.f;
    size_t wb = (size_t)bi * NN;
    wtsB[wb + j0] = to_bf16(e0 * inv);     // coalesced 2B stores
    wtsB[wb + j1] = to_bf16(e1 * inv);
    if (tid == 0) upd[bi] = (aspect[bi] != 0) && (mx > -1e37f);
}

// ---------------- kernel 3: MFMA agg, 2x2 register-blocked ----------------
// (verbatim R13/R14)
__global__ __launch_bounds__(256) void k_agg(const unsigned short* __restrict__ wtsB,
                                             const unsigned short* __restrict__ featT,
                                             const float* __restrict__ feat,
                                             const int* __restrict__ upd,
                                             float* __restrict__ out)
{
    int blk  = blockIdx.x;
    int b    = blk & 7;            // XCD pin
    int rem  = blk >> 3;           // 0..95
    int dblk = rem % 12;
    int iblk = rem / 12;           // 0..7

    int wave = threadIdx.x >> 6;
    int l    = threadIdx.x & 63;
    int i0w  = iblk * 64 + (wave >> 1) * 32;
    int d0w  = dblk * 64 + (wave & 1) * 32;
    int lr   = l & 15, lg = l >> 4;

    const unsigned short* wr0 = wtsB  + ((size_t)(b * NN + i0w + lr)) * NN + lg * 8;
    const unsigned short* wr1 = wr0 + 16 * NN;
    const unsigned short* fr0 = featT + ((size_t)(b * DD + d0w + lr)) * NN + lg * 8;
    const unsigned short* fr1 = fr0 + 16 * NN;

    f32x4 acc00 = {0.f,0.f,0.f,0.f}, acc01 = {0.f,0.f,0.f,0.f};
    f32x4 acc10 = {0.f,0.f,0.f,0.f}, acc11 = {0.f,0.f,0.f,0.f};

#pragma unroll
    for (int k = 0; k < NN; k += 32) {
        bf16x8 a0 = *(const bf16x8*)(wr0 + k);
        bf16x8 a1 = *(const bf16x8*)(wr1 + k);
        bf16x8 b0 = *(const bf16x8*)(fr0 + k);
        bf16x8 b1 = *(const bf16x8*)(fr1 + k);
        acc00 = __builtin_amdgcn_mfma_f32_16x16x32_bf16(a0, b0, acc00, 0, 0, 0);
        acc01 = __builtin_amdgcn_mfma_f32_16x16x32_bf16(a0, b1, acc01, 0, 0, 0);
        acc10 = __builtin_amdgcn_mfma_f32_16x16x32_bf16(a1, b0, acc10, 0, 0, 0);
        acc11 = __builtin_amdgcn_mfma_f32_16x16x32_bf16(a1, b1, acc11, 0, 0, 0);
    }

#pragma unroll
    for (int ai = 0; ai < 2; ++ai) {
#pragma unroll
        for (int reg = 0; reg < 4; ++reg) {
            int ii   = i0w + ai * 16 + lg * 4 + reg;
            int rowi = b * NN + ii;
            size_t rb = (size_t)rowi * DD;
            int up = upd[rowi];
            const f32x4& aL = ai ? acc10 : acc00;
            const f32x4& aR = ai ? acc11 : acc01;
            int c0 = d0w + lr, c1 = d0w + 16 + lr;
            out[rb + c0] = up ? aL[reg] : feat[rb + c0];
            out[rb + c1] = up ? aR[reg] : feat[rb + c1];
        }
    }
}

extern "C" void kernel_launch(void* const* d_in, const int* in_sizes, int n_in,
                              void* d_out, int out_size, void* d_ws, size_t ws_size,
                              hipStream_t stream)
{
    (void)in_sizes; (void)n_in; (void)out_size; (void)ws_size;
    const float* feat = (const float*)d_in[0];
    const int*   asp  = (const int*)d_in[1];
    const float* adj  = (const float*)d_in[2];
    const float* watt = (const float*)d_in[3];
    float* out = (float*)d_out;

    // workspace: wtsB bf16 [8][512][512] (4MB) | featT bf16 [8][768][512]
    // (6.3MB) | snbr | upd
    unsigned short* wtsB  = (unsigned short*)d_ws;
    unsigned short* featT = wtsB + (size_t)BB * NN * NN;
    float* snbr = (float*)(featT + (size_t)BB * DD * NN);
    int*   upd  = (int*)(snbr + BB * NN);

    k_prep<<<768 + 1024, 256, 0, stream>>>(feat, watt, featT, snbr);
    k_score<<<BB * NN, 256, 0, stream>>>(adj, snbr, asp, watt, wtsB, upd);
    k_agg<<<BB * (NN / 64) * (DD / 64), 256, 0, stream>>>(wtsB, featT, feat, upd, out);
}

// Round 16
// 120.526 us; speedup vs baseline: 2.1387x; 1.0179x over previous
//
#include <hip/hip_runtime.h>
#include <hip/hip_bf16.h>
#include <math.h>

#define BB    8
#define NN    512
#define DD    768
#define DEPD  64

typedef __attribute__((ext_vector_type(4))) float f32x4;
typedef __attribute__((ext_vector_type(8))) short bf16x8;

__device__ __forceinline__ unsigned short to_bf16(float x) {
    __hip_bfloat16 h = __float2bfloat16(x);       // RNE
    return __builtin_bit_cast(unsigned short, h);
}

// 16-lane-row sum via DPP (VALU pipe only); leaves the total in ALL 16 lanes.
__device__ __forceinline__ float dpp_sum16(float x) {
    int t;
    t = __builtin_amdgcn_update_dpp(0, __float_as_int(x), 0xB1, 0xF, 0xF, true);
    x += __int_as_float(t);
    t = __builtin_amdgcn_update_dpp(0, __float_as_int(x), 0x4E, 0xF, 0xF, true);
    x += __int_as_float(t);
    t = __builtin_amdgcn_update_dpp(0, __float_as_int(x), 0x141, 0xF, 0xF, true);
    x += __int_as_float(t);
    t = __builtin_amdgcn_update_dpp(0, __float_as_int(x), 0x140, 0xF, 0xF, true);
    x += __int_as_float(t);
    return x;
}

// ---------------- kernel 1: fused prep (verbatim R14/R15) -----------------
__global__ __launch_bounds__(256) void k_prep(const float* __restrict__ feat,
                                              const float* __restrict__ watt,
                                              unsigned short* __restrict__ featT,
                                              float* __restrict__ snbr)
{
    int blk = blockIdx.x;
    int t   = threadIdx.x;

    if (blk < 768) {                                  // ---- cast tile ----
        int b  = blk / 96;
        int j0 = ((blk / 12) % 8) * 64;
        int d0 = (blk % 12) * 64;

        __shared__ unsigned short lt[64][65];

        int dd = t & 63, j4 = t >> 6;
#pragma unroll
        for (int it = 0; it < 16; ++it) {
            int jj = j4 * 16 + it;
            float v = feat[((size_t)(b * NN) + (j0 + jj)) * DD + d0 + dd];
            lt[dd][jj] = to_bf16(v);
        }
        __syncthreads();

        int jj2 = t & 63, d4 = t >> 6;
#pragma unroll
        for (int it = 0; it < 16; ++it) {
            int dd2 = d4 * 16 + it;
            featT[((size_t)(b * DD) + (d0 + dd2)) * NN + j0 + jj2] = lt[dd2][jj2];
        }
    } else {                                          // ---- proj rows ----
        int pb   = blk - 768;                         // 0..1023
        int flat = pb * 4 + (t >> 6);                 // b*N + j
        int lane = t & 63;
        const float* frow = feat + (size_t)flat * DD + lane * 4;
        const float* wn   = watt + lane * 4;          // w_nbr = w[:768]
        float accn = 0.f;
#pragma unroll
        for (int k = 0; k < 3; ++k) {
            float4 f = *(const float4*)(frow + k * 256);
            float4 n = *(const float4*)(wn + k * 256);
            accn += f.x*n.x + f.y*n.y + f.z*n.z + f.w*n.w;
        }
#pragma unroll
        for (int off = 1; off < 64; off <<= 1)
            accn += __shfl_xor(accn, off);
        if (lane == 0) snbr[flat] = accn;
    }
}

// ---------------- kernel 2: sdep + masked softmax -> bf16 weights ---------
// (verbatim R15: non-temporal adj stream; measured at HBM roofline)
__global__ __launch_bounds__(256) void k_score(const float* __restrict__ adj,
                                               const float* __restrict__ snbr,
                                               const int* __restrict__ aspect,
                                               const float* __restrict__ watt,
                                               unsigned short* __restrict__ wtsB,
                                               int* __restrict__ upd)
{
    int bi  = blockIdx.x;          // b*N + i
    int b   = bi >> 9;
    int tid = threadIdx.x;
    int g = tid >> 4, l = tid & 15;

    __shared__ float sdep[NN];     // -INF = masked
    __shared__ float sred[4];

    float4 wd = *(const float4*)(watt + DD + l * 4);   // w_dep = w[768:832]

    const float* arow = adj + (size_t)bi * NN * DEPD;
#pragma unroll 4
    for (int it = 0; it < NN / 16; ++it) {
        int j = it * 16 + g;
        f32x4 a = __builtin_nontemporal_load(
                      (const f32x4*)(arow + (size_t)j * DEPD + l * 4));
        float p  = a[0]*wd.x + a[1]*wd.y + a[2]*wd.z + a[3]*wd.w;
        int   nz = (a[0] != 0.f) | (a[1] != 0.f) | (a[2] != 0.f) | (a[3] != 0.f);
        unsigned long long bal = __ballot(nz);
        unsigned int gnz = (unsigned int)((bal >> ((g & 3) * 16)) & 0xFFFFull);
        p = dpp_sum16(p);                              // VALU-only 16-lane sum
        if (l == 0) sdep[j] = gnz ? p : -INFINITY;
    }
    __syncthreads();

    int j0 = tid, j1 = tid + 256;
    float d0 = sdep[j0], d1 = sdep[j1];
    float sc0 = d0 + snbr[(b << 9) + j0];        // -INF stays -INF
    float sc1 = d1 + snbr[(b << 9) + j1];

    float v = fmaxf(sc0, sc1);
#pragma unroll
    for (int off = 1; off < 64; off <<= 1) v = fmaxf(v, __shfl_xor(v, off));
    if ((tid & 63) == 0) sred[tid >> 6] = v;
    __syncthreads();
    float mx = fmaxf(fmaxf(sred[0], sred[1]), fmaxf(sred[2], sred[3]));
    __syncthreads();

    float e0 = d0 > -1e37f ? __expf(sc0 - mx) : 0.f;
    float e1 = d1 > -1e37f ? __expf(sc1 - mx) : 0.f;
    v = e0 + e1;
#pragma unroll
    for (int off = 1; off < 64; off <<= 1) v += __shfl_xor(v, off);
    if ((tid & 63) == 0) sred[tid >> 6] = v;
    __syncthreads();
    float sm = sred[0] + sred[1] + sred[2] + sred[3];

    float inv = sm > 0.f ? 1.f / sm : 0.f;
    size_t wb = (size_t)bi * NN;
    wtsB[wb + j0] = to_bf16(e0 * inv);     // coalesced 2B stores
    wtsB[wb + j1] = to_bf16(e1 * inv);
    if (tid == 0) upd[bi] = (aspect[bi] != 0) && (mx > -1e37f);
}

// ---------------- kernel 3: MFMA agg, 2x2 register-blocked ----------------
// R13/R15 body; ONLY change: `out` stores are NON-TEMPORAL (write-only
// stream, don't let write-allocate evict featT/wtsB mid-kernel).
__global__ __launch_bounds__(256) void k_agg(const unsigned short* __restrict__ wtsB,
                                             const unsigned short* __restrict__ featT,
                                             const float* __restrict__ feat,
                                             const int* __restrict__ upd,
                                             float* __restrict__ out)
{
    int blk  = blockIdx.x;
    int b    = blk & 7;            // XCD pin
    int rem  = blk >> 3;           // 0..95
    int dblk = rem % 12;
    int iblk = rem / 12;           // 0..7

    int wave = threadIdx.x >> 6;
    int l    = threadIdx.x & 63;
    int i0w  = iblk * 64 + (wave >> 1) * 32;
    int d0w  = dblk * 64 + (wave & 1) * 32;
    int lr   = l & 15, lg = l >> 4;

    const unsigned short* wr0 = wtsB  + ((size_t)(b * NN + i0w + lr)) * NN + lg * 8;
    const unsigned short* wr1 = wr0 + 16 * NN;
    const unsigned short* fr0 = featT + ((size_t)(b * DD + d0w + lr)) * NN + lg * 8;
    const unsigned short* fr1 = fr0 + 16 * NN;

    f32x4 acc00 = {0.f,0.f,0.f,0.f}, acc01 = {0.f,0.f,0.f,0.f};
    f32x4 acc10 = {0.f,0.f,0.f,0.f}, acc11 = {0.f,0.f,0.f,0.f};

#pragma unroll
    for (int k = 0; k < NN; k += 32) {
        bf16x8 a0 = *(const bf16x8*)(wr0 + k);
        bf16x8 a1 = *(const bf16x8*)(wr1 + k);
        bf16x8 b0 = *(const bf16x8*)(fr0 + k);
        bf16x8 b1 = *(const bf16x8*)(fr1 + k);
        acc00 = __builtin_amdgcn_mfma_f32_16x16x32_bf16(a0, b0, acc00, 0, 0, 0);
        acc01 = __builtin_amdgcn_mfma_f32_16x16x32_bf16(a0, b1, acc01, 0, 0, 0);
        acc10 = __builtin_amdgcn_mfma_f32_16x16x32_bf16(a1, b0, acc10, 0, 0, 0);
        acc11 = __builtin_amdgcn_mfma_f32_16x16x32_bf16(a1, b1, acc11, 0, 0, 0);
    }

#pragma unroll
    for (int ai = 0; ai < 2; ++ai) {
#pragma unroll
        for (int reg = 0; reg < 4; ++reg) {
            int ii   = i0w + ai * 16 + lg * 4 + reg;
            int rowi = b * NN + ii;
            size_t rb = (size_t)rowi * DD;
            int up = upd[rowi];
            const f32x4& aL = ai ? acc10 : acc00;
            const f32x4& aR = ai ? acc11 : acc01;
            int c0 = d0w + lr, c1 = d0w + 16 + lr;
            float o0 = up ? aL[reg] : feat[rb + c0];
            float o1 = up ? aR[reg] : feat[rb + c1];
            __builtin_nontemporal_store(o0, out + rb + c0);
            __builtin_nontemporal_store(o1, out + rb + c1);
        }
    }
}

extern "C" void kernel_launch(void* const* d_in, const int* in_sizes, int n_in,
                              void* d_out, int out_size, void* d_ws, size_t ws_size,
                              hipStream_t stream)
{
    (void)in_sizes; (void)n_in; (void)out_size; (void)ws_size;
    const float* feat = (const float*)d_in[0];
    const int*   asp  = (const int*)d_in[1];
    const float* adj  = (const float*)d_in[2];
    const float* watt = (const float*)d_in[3];
    float* out = (float*)d_out;

    // workspace: wtsB bf16 [8][512][512] (4MB) | featT bf16 [8][768][512]
    // (6.3MB) | snbr | upd
    unsigned short* wtsB  = (unsigned short*)d_ws;
    unsigned short* featT = wtsB + (size_t)BB * NN * NN;
    float* snbr = (float*)(featT + (size_t)BB * DD * NN);
    int*   upd  = (int*)(snbr + BB * NN);

    k_prep<<<768 + 1024, 256, 0, stream>>>(feat, watt, featT, snbr);
    k_score<<<BB * NN, 256, 0, stream>>>(adj, snbr, asp, watt, wtsB, upd);
    k_agg<<<BB * (NN / 64) * (DD / 64), 256, 0, stream>>>(wtsB, featT, feat, upd, out);
}